// Round 1
// baseline (709.180 us; speedup 1.0000x reference)
//
#include <hip/hip_runtime.h>
#include <hip/hip_bf16.h>
#include <stdint.h>

#define NN 8192
#define DD 128

typedef float f32x4 __attribute__((ext_vector_type(4)));
typedef __bf16 bf16x8 __attribute__((ext_vector_type(8)));
typedef __bf16 bf16x4 __attribute__((ext_vector_type(4)));

__device__ __forceinline__ f32x4 mfma16(bf16x8 a, bf16x8 b, f32x4 c) {
    return __builtin_amdgcn_mfma_f32_16x16x32_bf16(a, b, c, 0, 0, 0);
}

__device__ __forceinline__ bf16x8 pack8(f32x4 lo, f32x4 hi) {
    bf16x8 r;
    r[0] = (__bf16)lo[0]; r[1] = (__bf16)lo[1]; r[2] = (__bf16)lo[2]; r[3] = (__bf16)lo[3];
    r[4] = (__bf16)hi[0]; r[5] = (__bf16)hi[1]; r[6] = (__bf16)hi[2]; r[7] = (__bf16)hi[3];
    return r;
}

__device__ __forceinline__ float fast_sigmoid(float x) {
    return __builtin_amdgcn_rcpf(1.0f + __expf(-x));
}

// ---------------- kernel 1: s = Z @ w_V (f32) ----------------
__global__ __launch_bounds__(256) void k_prep_s(
    const float* __restrict__ Z, const float* __restrict__ wV, float* __restrict__ s)
{
    const int wid  = threadIdx.x >> 6;
    const int lane = threadIdx.x & 63;
    const int row  = blockIdx.x * 4 + wid;
    float p = Z[row * DD + lane] * wV[lane] + Z[row * DD + 64 + lane] * wV[64 + lane];
    #pragma unroll
    for (int off = 32; off > 0; off >>= 1) p += __shfl_xor(p, off, 64);
    if (lane == 0) s[row] = p;
}

// ---------------- kernel 2: small GEMMs -> XDT, YT (bf16), REA=delta*rea (f32) ----------------
__global__ __launch_bounds__(256) void k_prep_small(
    const float* __restrict__ Z, const float* __restrict__ W_D,
    const float* __restrict__ W_C, const float* __restrict__ W1,
    const float* __restrict__ b1, const float* __restrict__ W2,
    const float* __restrict__ b2, const float* __restrict__ delta_logit,
    __bf16* __restrict__ XDT, __bf16* __restrict__ YT, float* __restrict__ REA)
{
    __shared__ __bf16 Hs[64][136];   // +8 bf16 pad: keeps b128 reads 16B-aligned, ~conflict-free
    const int tid = threadIdx.x;
    const int w = tid >> 6, l = tid & 63;
    const int lr = l & 15, lg = l >> 4;
    const int r0 = blockIdx.x * 64;
    const int arow = r0 + 16 * w + lr;

    const f32x4 zero4 = {0.f, 0.f, 0.f, 0.f};
    f32x4 aXD[8], aY[8], aH[8];
    #pragma unroll
    for (int i = 0; i < 8; ++i) { aXD[i] = zero4; aY[i] = zero4; aH[i] = zero4; }

    // layer-1 GEMMs: X_D = Z@W_D^T, Y = Z@W_C^T, Hpre = Z@W1^T  (share A fragments)
    #pragma unroll
    for (int t = 0; t < 4; ++t) {
        const int k0 = 32 * t + 8 * lg;
        const f32x4 za = *(const f32x4*)(Z + arow * DD + k0);
        const f32x4 zb = *(const f32x4*)(Z + arow * DD + k0 + 4);
        const bf16x8 af = pack8(za, zb);
        #pragma unroll
        for (int nf = 0; nf < 8; ++nf) {
            const int wrow = 16 * nf + lr;
            const bf16x8 bd = pack8(*(const f32x4*)(W_D + wrow * DD + k0),
                                    *(const f32x4*)(W_D + wrow * DD + k0 + 4));
            aXD[nf] = mfma16(af, bd, aXD[nf]);
            const bf16x8 bc = pack8(*(const f32x4*)(W_C + wrow * DD + k0),
                                    *(const f32x4*)(W_C + wrow * DD + k0 + 4));
            aY[nf] = mfma16(af, bc, aY[nf]);
            const bf16x8 bw1 = pack8(*(const f32x4*)(W1 + wrow * DD + k0),
                                     *(const f32x4*)(W1 + wrow * DD + k0 + 4));
            aH[nf] = mfma16(af, bw1, aH[nf]);
        }
    }

    // write transposed bf16 panels + tanh hidden to LDS
    #pragma unroll
    for (int nf = 0; nf < 8; ++nf) {
        const int col = 16 * nf + lr;
        const float bb1 = b1[col];
        #pragma unroll
        for (int r = 0; r < 4; ++r) {
            const int orow = r0 + 16 * w + 4 * lg + r;
            XDT[col * NN + orow] = (__bf16)aXD[nf][r];
            YT[col * NN + orow]  = (__bf16)aY[nf][r];
            const float x = aH[nf][r] + bb1;
            const float e = __expf(2.0f * x);
            const float th = 1.0f - 2.0f * __builtin_amdgcn_rcpf(e + 1.0f);
            Hs[16 * w + 4 * lg + r][col] = (__bf16)th;
        }
    }
    __syncthreads();

    // layer-2: rea = H @ W2^T
    f32x4 aR[8];
    #pragma unroll
    for (int i = 0; i < 8; ++i) aR[i] = zero4;
    #pragma unroll
    for (int t = 0; t < 4; ++t) {
        const int k0 = 32 * t + 8 * lg;
        const bf16x8 hf = *(const bf16x8*)(&Hs[16 * w + lr][k0]);
        #pragma unroll
        for (int nf = 0; nf < 8; ++nf) {
            const int wrow = 16 * nf + lr;
            const bf16x8 bw2 = pack8(*(const f32x4*)(W2 + wrow * DD + k0),
                                     *(const f32x4*)(W2 + wrow * DD + k0 + 4));
            aR[nf] = mfma16(hf, bw2, aR[nf]);
        }
    }
    const float delta = fast_sigmoid(delta_logit[0]);
    #pragma unroll
    for (int nf = 0; nf < 8; ++nf) {
        const int col = 16 * nf + lr;
        const float bb2 = b2[col];
        #pragma unroll
        for (int r = 0; r < 4; ++r) {
            const int orow = r0 + 16 * w + 4 * lg + r;
            REA[orow * DD + col] = delta * (aR[nf][r] + bb2);
        }
    }
}

// ---------------- kernel 3: fused dif + con GEMMs over K=8192 ----------------
// grid (2, 256): x = col-half (64 cols), y = row-block (32 rows). 4 waves: wr=wid>>1, wc=wid&1.
__global__ __launch_bounds__(256, 2) void k_big(
    const float* __restrict__ A, const float* __restrict__ s,
    const __bf16* __restrict__ XDT, const __bf16* __restrict__ YT,
    const float* __restrict__ REA, const float* __restrict__ omega_logit,
    float* __restrict__ out)
{
    __shared__ uint32_t Gs[1024];    // 2 bufs x [wr(2)][lane(64)][16B] = 4KB, frag-layout g tiles
    const int tid = threadIdx.x;
    const int wid = tid >> 6, l = tid & 63;
    const int wr = wid >> 1, wc = wid & 1;
    const int lr = l & 15, lg = l >> 4;
    const int r0 = blockIdx.y * 32;
    const int colbase = blockIdx.x * 64 + wc * 32;

    // g-writer role: 256 threads cover the 32x32 g tile (4 values each)
    const int wrw = tid >> 7;
    const int q   = tid & 127;
    const int wl  = q >> 1, e4 = q & 1;
    const float s_i = s[r0 + 16 * wrw + (wl & 15)];
    const int gslot_base = wrw * 256 + wl * 4 + e4 * 2;      // word index within a buffer

    const float* ap  = A + (size_t)(r0 + 16 * wr + lr) * NN + 8 * lg;
    const float* sp  = s + 8 * (wl >> 4) + 4 * e4;
    const __bf16* xp0 = XDT + (size_t)(colbase + lr) * NN + 8 * lg;
    const __bf16* xp1 = XDT + (size_t)(colbase + 16 + lr) * NN + 8 * lg;
    const __bf16* yp0 = YT + (size_t)(colbase + lr) * NN + 8 * lg;
    const __bf16* yp1 = YT + (size_t)(colbase + 16 + lr) * NN + 8 * lg;

    const f32x4 zero4 = {0.f, 0.f, 0.f, 0.f};
    f32x4 accD0 = zero4, accD1 = zero4, accC0 = zero4, accC1 = zero4, accDen = zero4;

    bf16x8 ones;
    #pragma unroll
    for (int i = 0; i < 8; ++i) ones[i] = (__bf16)1.0f;

    // ---- prologue: load tile 0, compute g(0) into buffer 0 ----
    f32x4 a0 = *(const f32x4*)(ap);
    f32x4 a1 = *(const f32x4*)(ap + 4);
    bf16x8 bx0 = *(const bf16x8*)(xp0);
    bf16x8 bx1 = *(const bf16x8*)(xp1);
    bf16x8 by0 = *(const bf16x8*)(yp0);
    bf16x8 by1 = *(const bf16x8*)(yp1);
    {
        const f32x4 sj0 = *(const f32x4*)(sp);
        bf16x4 gb;
        #pragma unroll
        for (int j = 0; j < 4; ++j) {
            const float x = s_i - sj0[j];
            gb[j] = (__bf16)__expf(fast_sigmoid(x));
        }
        union { bf16x4 b; uint32_t u[2]; } gu; gu.b = gb;
        Gs[gslot_base] = gu.u[0];
        Gs[gslot_base + 1] = gu.u[1];
    }
    ap += 32; sp += 32; xp0 += 32; xp1 += 32; yp0 += 32; yp1 += 32;

    for (int t = 0; t < 256; ++t) {
        // issue next-tile loads (at t>=254 these re-read tile 255; values unused)
        const f32x4 a0n = *(const f32x4*)(ap);
        const f32x4 a1n = *(const f32x4*)(ap + 4);
        const f32x4 sjn = *(const f32x4*)(sp);
        const bf16x8 bx0n = *(const bf16x8*)(xp0);
        const bf16x8 bx1n = *(const bf16x8*)(xp1);
        const bf16x8 by0n = *(const bf16x8*)(yp0);
        const bf16x8 by1n = *(const bf16x8*)(yp1);

        __syncthreads();   // g(t) visible; previous-iter readers done with buf (t+1)&1

        // read g fragment for tile t
        const bf16x8 gf = *(const bf16x8*)(&Gs[(t & 1) * 512 + wr * 256 + l * 4]);

        // compute g(t+1) into the other buffer
        {
            bf16x4 gb;
            #pragma unroll
            for (int j = 0; j < 4; ++j) {
                const float x = s_i - sjn[j];
                gb[j] = (__bf16)__expf(fast_sigmoid(x));
            }
            union { bf16x4 b; uint32_t u[2]; } gu; gu.b = gb;
            const int wbase = ((t + 1) & 1) * 512 + gslot_base;
            Gs[wbase] = gu.u[0];
            Gs[wbase + 1] = gu.u[1];
        }

        // MFMAs for tile t
        const bf16x8 af = pack8(a0, a1);
        accD0 = mfma16(af, bx0, accD0);
        accD1 = mfma16(af, bx1, accD1);
        accC0 = mfma16(gf, by0, accC0);
        accC1 = mfma16(gf, by1, accC1);
        accDen = mfma16(gf, ones, accDen);

        // rotate
        a0 = a0n; a1 = a1n;
        bx0 = bx0n; bx1 = bx1n; by0 = by0n; by1 = by1n;
        if (t < 254) { ap += 32; sp += 32; xp0 += 32; xp1 += 32; yp0 += 32; yp1 += 32; }
    }

    // ---- epilogue ----
    const float omega = fast_sigmoid(omega_logit[0]);
    #pragma unroll
    for (int nf = 0; nf < 2; ++nf) {
        const f32x4 ad = nf ? accD1 : accD0;
        const f32x4 ac = nf ? accC1 : accC0;
        const int col = colbase + 16 * nf + lr;
        #pragma unroll
        for (int r = 0; r < 4; ++r) {
            const int orow = r0 + 16 * wr + 4 * lg + r;
            const float dv = fmaxf(ad[r], 0.0f);
            const float cv = ac[r] * __builtin_amdgcn_rcpf(accDen[r]);
            out[orow * DD + col] = REA[orow * DD + col] + omega * dv + (1.0f - omega) * cv;
        }
    }
}

extern "C" void kernel_launch(void* const* d_in, const int* in_sizes, int n_in,
                              void* d_out, int out_size, void* d_ws, size_t ws_size,
                              hipStream_t stream) {
    (void)in_sizes; (void)n_in; (void)out_size; (void)ws_size;
    const float* Z   = (const float*)d_in[0];
    const float* A   = (const float*)d_in[1];
    const float* W_D = (const float*)d_in[2];
    const float* W_C = (const float*)d_in[3];
    const float* wV  = (const float*)d_in[4];
    const float* W1  = (const float*)d_in[5];
    const float* b1  = (const float*)d_in[6];
    const float* W2  = (const float*)d_in[7];
    const float* b2  = (const float*)d_in[8];
    const float* omega_logit = (const float*)d_in[9];
    const float* delta_logit = (const float*)d_in[10];
    float* out = (float*)d_out;

    // ws layout: s (32KB) | XDT bf16 2MB | YT bf16 2MB | REA f32 4MB  (total ~8.04MB)
    float*  s_ws = (float*)d_ws;
    __bf16* XDT  = (__bf16*)((char*)d_ws + 32768);
    __bf16* YT   = (__bf16*)((char*)d_ws + 32768 + 2097152);
    float*  REA  = (float*)((char*)d_ws + 32768 + 2 * 2097152);

    k_prep_s<<<dim3(2048), dim3(256), 0, stream>>>(Z, wV, s_ws);
    k_prep_small<<<dim3(128), dim3(256), 0, stream>>>(Z, W_D, W_C, W1, b1, W2, b2,
                                                      delta_logit, XDT, YT, REA);
    k_big<<<dim3(2, 256), dim3(256), 0, stream>>>(A, s_ws, XDT, YT, REA, omega_logit, out);
}

// Round 2
// 705.680 us; speedup vs baseline: 1.0050x; 1.0050x over previous
//
#include <hip/hip_runtime.h>
#include <hip/hip_bf16.h>
#include <stdint.h>

#define NN 8192
#define DD 128

typedef float f32x4 __attribute__((ext_vector_type(4)));
typedef __bf16 bf16x8 __attribute__((ext_vector_type(8)));
typedef __bf16 bf16x4 __attribute__((ext_vector_type(4)));

__device__ __forceinline__ f32x4 mfma16(bf16x8 a, bf16x8 b, f32x4 c) {
    return __builtin_amdgcn_mfma_f32_16x16x32_bf16(a, b, c, 0, 0, 0);
}

__device__ __forceinline__ bf16x8 pack8(f32x4 lo, f32x4 hi) {
    bf16x8 r;
    r[0] = (__bf16)lo[0]; r[1] = (__bf16)lo[1]; r[2] = (__bf16)lo[2]; r[3] = (__bf16)lo[3];
    r[4] = (__bf16)hi[0]; r[5] = (__bf16)hi[1]; r[6] = (__bf16)hi[2]; r[7] = (__bf16)hi[3];
    return r;
}

__device__ __forceinline__ float fast_sigmoid(float x) {
    return __builtin_amdgcn_rcpf(1.0f + __expf(-x));
}

// ---------------- kernel 1: E = exp(Z @ w_V) ----------------
__global__ __launch_bounds__(256) void k_prep_sE(
    const float* __restrict__ Z, const float* __restrict__ wV, float* __restrict__ E)
{
    const int wid  = threadIdx.x >> 6;
    const int lane = threadIdx.x & 63;
    const int row  = blockIdx.x * 4 + wid;
    float p = Z[row * DD + lane] * wV[lane] + Z[row * DD + 64 + lane] * wV[64 + lane];
    #pragma unroll
    for (int off = 32; off > 0; off >>= 1) p += __shfl_xor(p, off, 64);
    if (lane == 0) E[row] = __expf(p);
}

// ---------------- kernel 2: W_D|W_C|W1|W2 -> bf16 (concatenated) ----------------
__global__ __launch_bounds__(256) void k_conv_w(
    const float* __restrict__ W_D, const float* __restrict__ W_C,
    const float* __restrict__ W1, const float* __restrict__ W2,
    __bf16* __restrict__ Wb)
{
    const int t = blockIdx.x * 256 + threadIdx.x;    // 0..16383
    const int m = t >> 12, i = t & 4095;
    const float* src = (m == 0) ? W_D : (m == 1) ? W_C : (m == 2) ? W1 : W2;
    const f32x4 v = *(const f32x4*)(src + i * 4);
    bf16x4 b;
    b[0] = (__bf16)v[0]; b[1] = (__bf16)v[1]; b[2] = (__bf16)v[2]; b[3] = (__bf16)v[3];
    *(bf16x4*)(Wb + m * 16384 + i * 4) = b;
}

// ---------------- kernel 3: XDT/YT (bf16 [col][row]), REAT = delta*rea (bf16 [col][row]) ----------------
__global__ __launch_bounds__(256) void k_prep2(
    const float* __restrict__ Z, const __bf16* __restrict__ Wb,
    const float* __restrict__ b1, const float* __restrict__ b2,
    const float* __restrict__ delta_logit,
    __bf16* __restrict__ XDT, __bf16* __restrict__ YT, __bf16* __restrict__ REAT)
{
    __shared__ __bf16 Hs[32][136];
    const int tid = threadIdx.x;
    const int w = tid >> 6, l = tid & 63;
    const int lr = l & 15, lg = l >> 4;
    const int wr = w & 1, wn = w >> 1;
    const int r0 = blockIdx.x * 32;
    const int arow = r0 + 16 * wr + lr;
    const __bf16* WDb = Wb;
    const __bf16* WCb = Wb + 16384;
    const __bf16* W1b = Wb + 32768;
    const __bf16* W2b = Wb + 49152;

    const f32x4 zero4 = {0.f, 0.f, 0.f, 0.f};
    f32x4 aXD[4], aY[4], aH[4];
    #pragma unroll
    for (int i = 0; i < 4; ++i) { aXD[i] = zero4; aY[i] = zero4; aH[i] = zero4; }

    #pragma unroll
    for (int t = 0; t < 4; ++t) {
        const int k0 = 32 * t + 8 * lg;
        const bf16x8 af = pack8(*(const f32x4*)(Z + arow * DD + k0),
                                *(const f32x4*)(Z + arow * DD + k0 + 4));
        #pragma unroll
        for (int nf = 0; nf < 4; ++nf) {
            const int col = 64 * wn + 16 * nf + lr;
            aXD[nf] = mfma16(af, *(const bf16x8*)(WDb + col * DD + k0), aXD[nf]);
            aY[nf]  = mfma16(af, *(const bf16x8*)(WCb + col * DD + k0), aY[nf]);
            aH[nf]  = mfma16(af, *(const bf16x8*)(W1b + col * DD + k0), aH[nf]);
        }
    }

    const int orow = r0 + 16 * wr + 4 * lg;
    #pragma unroll
    for (int nf = 0; nf < 4; ++nf) {
        const int col = 64 * wn + 16 * nf + lr;
        bf16x4 xo, yo;
        const float bb1 = b1[col];
        #pragma unroll
        for (int r = 0; r < 4; ++r) {
            xo[r] = (__bf16)aXD[nf][r];
            yo[r] = (__bf16)aY[nf][r];
            const float x = aH[nf][r] + bb1;
            const float e = __expf(2.0f * x);
            Hs[16 * wr + 4 * lg + r][col] = (__bf16)(1.0f - 2.0f * __builtin_amdgcn_rcpf(e + 1.0f));
        }
        *(bf16x4*)(XDT + (size_t)col * NN + orow) = xo;
        *(bf16x4*)(YT  + (size_t)col * NN + orow) = yo;
    }
    __syncthreads();

    f32x4 aR[4];
    #pragma unroll
    for (int i = 0; i < 4; ++i) aR[i] = zero4;
    #pragma unroll
    for (int t = 0; t < 4; ++t) {
        const int k0 = 32 * t + 8 * lg;
        const bf16x8 hf = *(const bf16x8*)(&Hs[16 * wr + lr][k0]);
        #pragma unroll
        for (int nf = 0; nf < 4; ++nf) {
            const int col = 64 * wn + 16 * nf + lr;
            aR[nf] = mfma16(hf, *(const bf16x8*)(W2b + col * DD + k0), aR[nf]);
        }
    }
    const float delta = fast_sigmoid(delta_logit[0]);
    #pragma unroll
    for (int nf = 0; nf < 4; ++nf) {
        const int col = 64 * wn + 16 * nf + lr;
        const float bb2 = b2[col];
        bf16x4 ro;
        #pragma unroll
        for (int r = 0; r < 4; ++r) ro[r] = (__bf16)(delta * (aR[nf][r] + bb2));
        *(bf16x4*)(REAT + (size_t)col * NN + orow) = ro;
    }
}

// ---------------- kernel 4: fused dif + con, barrier-free K-loop, in-block K-split ----------------
// grid 256 row-blocks (32 rows), 1024 threads = 16 waves: wc(4) x wr(2) x kh(2).
// wave: 16 rows x 32 cols, K = 4096 (128 steps of 32). Partials reduced via LDS at the end.
__global__ __launch_bounds__(1024) void k_big(
    const float* __restrict__ A, const float* __restrict__ E,
    const __bf16* __restrict__ XDT, const __bf16* __restrict__ YT,
    const __bf16* __restrict__ REAT, const float* __restrict__ omega_logit,
    float* __restrict__ out)
{
    __shared__ float red[8][64][20];   // 40KB: [wr*4+wc][lane][5 frags x 4]
    const int tid = threadIdx.x;
    const int wid = tid >> 6, l = tid & 63;
    const int lr = l & 15, lg = l >> 4;
    const int wc = wid & 3, wr = (wid >> 2) & 1, kh = wid >> 3;
    const int r0 = blockIdx.x * 32;
    const int row = r0 + 16 * wr + lr;
    const int colbase = 32 * wc;
    const int kstart = kh * 4096;

    const float* ap = A + (size_t)row * NN + kstart + 8 * lg;
    const float* ep = E + kstart + 8 * lg;
    const __bf16* xp0 = XDT + (size_t)(colbase + lr) * NN + kstart + 8 * lg;
    const __bf16* xp1 = xp0 + (size_t)16 * NN;
    const __bf16* yp0 = YT + (size_t)(colbase + lr) * NN + kstart + 8 * lg;
    const __bf16* yp1 = yp0 + (size_t)16 * NN;
    const float u = E[row];

    const f32x4 zero4 = {0.f, 0.f, 0.f, 0.f};
    f32x4 accD0 = zero4, accD1 = zero4, accC0 = zero4, accC1 = zero4, accDen = zero4;
    bf16x8 ones;
    #pragma unroll
    for (int i = 0; i < 8; ++i) ones[i] = (__bf16)1.0f;

    // prologue: tile 0 in regs
    f32x4 a0 = *(const f32x4*)(ap), a1 = *(const f32x4*)(ap + 4);
    f32x4 e0 = *(const f32x4*)(ep), e1 = *(const f32x4*)(ep + 4);
    bf16x8 bx0 = *(const bf16x8*)(xp0), bx1 = *(const bf16x8*)(xp1);
    bf16x8 by0 = *(const bf16x8*)(yp0), by1 = *(const bf16x8*)(yp1);

    for (int t = 0; t < 128; ++t) {
        const int adv = (t < 127) ? 32 : 0;
        // prefetch tile t+1 (all streams; no barriers anywhere)
        const f32x4 a0n = *(const f32x4*)(ap + adv);
        const f32x4 a1n = *(const f32x4*)(ap + adv + 4);
        const f32x4 e0n = *(const f32x4*)(ep + adv);
        const f32x4 e1n = *(const f32x4*)(ep + adv + 4);
        const bf16x8 bx0n = *(const bf16x8*)(xp0 + adv);
        const bf16x8 bx1n = *(const bf16x8*)(xp1 + adv);
        const bf16x8 by0n = *(const bf16x8*)(yp0 + adv);
        const bf16x8 by1n = *(const bf16x8*)(yp1 + adv);

        // g fragment in-register: g[lr][8*lg+e] = exp(u/(u+E_j))
        bf16x8 gf;
        #pragma unroll
        for (int j = 0; j < 4; ++j) {
            const float sg0 = u * __builtin_amdgcn_rcpf(u + e0[j]);
            gf[j] = (__bf16)__expf(sg0);
            const float sg1 = u * __builtin_amdgcn_rcpf(u + e1[j]);
            gf[4 + j] = (__bf16)__expf(sg1);
        }
        const bf16x8 af = pack8(a0, a1);

        accD0 = mfma16(af, bx0, accD0);
        accD1 = mfma16(af, bx1, accD1);
        accC0 = mfma16(gf, by0, accC0);
        accC1 = mfma16(gf, by1, accC1);
        accDen = mfma16(gf, ones, accDen);

        a0 = a0n; a1 = a1n; e0 = e0n; e1 = e1n;
        bx0 = bx0n; bx1 = bx1n; by0 = by0n; by1 = by1n;
        ap += adv; ep += adv; xp0 += adv; xp1 += adv; yp0 += adv; yp1 += adv;
    }

    // ---- cross-kh reduction via LDS (single barrier in whole kernel) ----
    const int grp = wr * 4 + wc;
    if (kh == 1) {
        float* slot = &red[grp][l][0];
        *(f32x4*)(slot + 0)  = accD0;
        *(f32x4*)(slot + 4)  = accD1;
        *(f32x4*)(slot + 8)  = accC0;
        *(f32x4*)(slot + 12) = accC1;
        *(f32x4*)(slot + 16) = accDen;
    }
    __syncthreads();
    if (kh == 0) {
        const float* slot = &red[grp][l][0];
        accD0 += *(const f32x4*)(slot + 0);
        accD1 += *(const f32x4*)(slot + 4);
        accC0 += *(const f32x4*)(slot + 8);
        accC1 += *(const f32x4*)(slot + 12);
        accDen += *(const f32x4*)(slot + 16);

        const float omega = fast_sigmoid(omega_logit[0]);
        const float om1 = 1.0f - omega;
        const int rbase = r0 + 16 * wr + 4 * lg;
        #pragma unroll
        for (int nf = 0; nf < 2; ++nf) {
            const f32x4 ad = nf ? accD1 : accD0;
            const f32x4 ac = nf ? accC1 : accC0;
            const int col = colbase + 16 * nf + lr;
            const bf16x4 rea4 = *(const bf16x4*)(REAT + (size_t)col * NN + rbase);
            #pragma unroll
            for (int r = 0; r < 4; ++r) {
                const float dv = fmaxf(ad[r], 0.0f);
                const float cv = ac[r] * __builtin_amdgcn_rcpf(accDen[r]);
                out[(size_t)(rbase + r) * DD + col] = (float)rea4[r] + omega * dv + om1 * cv;
            }
        }
    }
}

extern "C" void kernel_launch(void* const* d_in, const int* in_sizes, int n_in,
                              void* d_out, int out_size, void* d_ws, size_t ws_size,
                              hipStream_t stream) {
    (void)in_sizes; (void)n_in; (void)out_size; (void)ws_size;
    const float* Z   = (const float*)d_in[0];
    const float* A   = (const float*)d_in[1];
    const float* W_D = (const float*)d_in[2];
    const float* W_C = (const float*)d_in[3];
    const float* wV  = (const float*)d_in[4];
    const float* W1  = (const float*)d_in[5];
    const float* b1  = (const float*)d_in[6];
    const float* W2  = (const float*)d_in[7];
    const float* b2  = (const float*)d_in[8];
    const float* omega_logit = (const float*)d_in[9];
    const float* delta_logit = (const float*)d_in[10];
    float* out = (float*)d_out;

    // ws layout: E 32KB | Wb (4x32KB bf16) | XDT 2MB | YT 2MB | REAT 2MB  (~6.5MB)
    float*  E    = (float*)d_ws;
    __bf16* Wb   = (__bf16*)((char*)d_ws + 32768);
    __bf16* XDT  = (__bf16*)((char*)d_ws + 262144);
    __bf16* YT   = (__bf16*)((char*)d_ws + 262144 + 2097152);
    __bf16* REAT = (__bf16*)((char*)d_ws + 262144 + 2 * 2097152);

    k_prep_sE<<<dim3(2048), dim3(256), 0, stream>>>(Z, wV, E);
    k_conv_w<<<dim3(64), dim3(256), 0, stream>>>(W_D, W_C, W1, W2, Wb);
    k_prep2<<<dim3(256), dim3(256), 0, stream>>>(Z, Wb, b1, b2, delta_logit, XDT, YT, REAT);
    k_big<<<dim3(256), dim3(1024), 0, stream>>>(A, E, XDT, YT, REAT, omega_logit, out);
}

// Round 3
// 538.748 us; speedup vs baseline: 1.3163x; 1.3099x over previous
//
#include <hip/hip_runtime.h>
#include <hip/hip_bf16.h>
#include <stdint.h>

#define NN 8192
#define DD 128

typedef float f32x4 __attribute__((ext_vector_type(4)));
typedef __bf16 bf16x8 __attribute__((ext_vector_type(8)));
typedef __bf16 bf16x4 __attribute__((ext_vector_type(4)));

__device__ __forceinline__ f32x4 mfma16(bf16x8 a, bf16x8 b, f32x4 c) {
    return __builtin_amdgcn_mfma_f32_16x16x32_bf16(a, b, c, 0, 0, 0);
}

__device__ __forceinline__ bf16x8 pack8(f32x4 lo, f32x4 hi) {
    bf16x8 r;
    r[0] = (__bf16)lo[0]; r[1] = (__bf16)lo[1]; r[2] = (__bf16)lo[2]; r[3] = (__bf16)lo[3];
    r[4] = (__bf16)hi[0]; r[5] = (__bf16)hi[1]; r[6] = (__bf16)hi[2]; r[7] = (__bf16)hi[3];
    return r;
}

__device__ __forceinline__ float fast_sigmoid(float x) {
    return __builtin_amdgcn_rcpf(1.0f + __expf(-x));
}

// ---------------- kernel 1: E = exp(Z @ w_V) ----------------
__global__ __launch_bounds__(256) void k_prep_sE(
    const float* __restrict__ Z, const float* __restrict__ wV, float* __restrict__ E)
{
    const int wid  = threadIdx.x >> 6;
    const int lane = threadIdx.x & 63;
    const int row  = blockIdx.x * 4 + wid;
    float p = Z[row * DD + lane] * wV[lane] + Z[row * DD + 64 + lane] * wV[64 + lane];
    #pragma unroll
    for (int off = 32; off > 0; off >>= 1) p += __shfl_xor(p, off, 64);
    if (lane == 0) E[row] = __expf(p);
}

// ---------------- kernel 2: W_D|W_C|W1|W2 -> bf16 (concatenated) ----------------
__global__ __launch_bounds__(256) void k_conv_w(
    const float* __restrict__ W_D, const float* __restrict__ W_C,
    const float* __restrict__ W1, const float* __restrict__ W2,
    __bf16* __restrict__ Wb)
{
    const int t = blockIdx.x * 256 + threadIdx.x;    // 0..16383
    const int m = t >> 12, i = t & 4095;
    const float* src = (m == 0) ? W_D : (m == 1) ? W_C : (m == 2) ? W1 : W2;
    const f32x4 v = *(const f32x4*)(src + i * 4);
    bf16x4 b;
    b[0] = (__bf16)v[0]; b[1] = (__bf16)v[1]; b[2] = (__bf16)v[2]; b[3] = (__bf16)v[3];
    *(bf16x4*)(Wb + m * 16384 + i * 4) = b;
}

// ---------------- kernel 3: XB/YB (bf16, blocked fragment-major), REAT (bf16 [col][row]) ----
// Blocked layout: element (k, col) of X stored at  (k>>5)*4096 + col*32 + (k&31).
// A 32k x 128col tile is 8KB contiguous; an MFMA B-fragment wave-load is 1KB contiguous.
__global__ __launch_bounds__(256) void k_prep2(
    const float* __restrict__ Z, const __bf16* __restrict__ Wb,
    const float* __restrict__ b1, const float* __restrict__ b2,
    const float* __restrict__ delta_logit,
    __bf16* __restrict__ XB, __bf16* __restrict__ YB, __bf16* __restrict__ REAT)
{
    __shared__ __bf16 Hs[32][136];
    const int tid = threadIdx.x;
    const int w = tid >> 6, l = tid & 63;
    const int lr = l & 15, lg = l >> 4;
    const int wr = w & 1, wn = w >> 1;
    const int r0 = blockIdx.x * 32;
    const int arow = r0 + 16 * wr + lr;
    const __bf16* WDb = Wb;
    const __bf16* WCb = Wb + 16384;
    const __bf16* W1b = Wb + 32768;
    const __bf16* W2b = Wb + 49152;

    const f32x4 zero4 = {0.f, 0.f, 0.f, 0.f};
    f32x4 aXD[4], aY[4], aH[4];
    #pragma unroll
    for (int i = 0; i < 4; ++i) { aXD[i] = zero4; aY[i] = zero4; aH[i] = zero4; }

    #pragma unroll
    for (int t = 0; t < 4; ++t) {
        const int k0 = 32 * t + 8 * lg;
        const bf16x8 af = pack8(*(const f32x4*)(Z + arow * DD + k0),
                                *(const f32x4*)(Z + arow * DD + k0 + 4));
        #pragma unroll
        for (int nf = 0; nf < 4; ++nf) {
            const int col = 64 * wn + 16 * nf + lr;
            aXD[nf] = mfma16(af, *(const bf16x8*)(WDb + col * DD + k0), aXD[nf]);
            aY[nf]  = mfma16(af, *(const bf16x8*)(WCb + col * DD + k0), aY[nf]);
            aH[nf]  = mfma16(af, *(const bf16x8*)(W1b + col * DD + k0), aH[nf]);
        }
    }

    const int orow = r0 + 16 * wr + 4 * lg;     // k-index of big GEMM; 4-aligned
    const int tile = orow >> 5, kin = orow & 31;
    #pragma unroll
    for (int nf = 0; nf < 4; ++nf) {
        const int col = 64 * wn + 16 * nf + lr;
        bf16x4 xo, yo;
        const float bb1 = b1[col];
        #pragma unroll
        for (int r = 0; r < 4; ++r) {
            xo[r] = (__bf16)aXD[nf][r];
            yo[r] = (__bf16)aY[nf][r];
            const float x = aH[nf][r] + bb1;
            const float e = __expf(2.0f * x);
            Hs[16 * wr + 4 * lg + r][col] = (__bf16)(1.0f - 2.0f * __builtin_amdgcn_rcpf(e + 1.0f));
        }
        *(bf16x4*)(XB + tile * 4096 + col * 32 + kin) = xo;
        *(bf16x4*)(YB + tile * 4096 + col * 32 + kin) = yo;
    }
    __syncthreads();

    f32x4 aR[4];
    #pragma unroll
    for (int i = 0; i < 4; ++i) aR[i] = zero4;
    #pragma unroll
    for (int t = 0; t < 4; ++t) {
        const int k0 = 32 * t + 8 * lg;
        const bf16x8 hf = *(const bf16x8*)(&Hs[16 * wr + lr][k0]);
        #pragma unroll
        for (int nf = 0; nf < 4; ++nf) {
            const int col = 64 * wn + 16 * nf + lr;
            aR[nf] = mfma16(hf, *(const bf16x8*)(W2b + col * DD + k0), aR[nf]);
        }
    }
    const float delta = fast_sigmoid(delta_logit[0]);
    #pragma unroll
    for (int nf = 0; nf < 4; ++nf) {
        const int col = 64 * wn + 16 * nf + lr;
        const float bb2 = b2[col];
        bf16x4 ro;
        #pragma unroll
        for (int r = 0; r < 4; ++r) ro[r] = (__bf16)(delta * (aR[nf][r] + bb2));
        *(bf16x4*)(REAT + (size_t)col * NN + orow) = ro;
    }
}

// ---------------- kernel 4: fused dif + con ----------------
// grid 256 row-blocks (32 rows), 512 threads = 8 waves: wc(2) x wr(2) x kh(2).
// wave: 16 rows x 64 cols, K = 4096 (128 tiles of 32). Explicit 2-deep named register
// double-buffer (unroll-2), barrier-free main loop, one LDS reduce at the end.
__global__ __launch_bounds__(512, 2) void k_big(
    const float* __restrict__ A, const float* __restrict__ E,
    const __bf16* __restrict__ XB, const __bf16* __restrict__ YB,
    const __bf16* __restrict__ REAT, const float* __restrict__ omega_logit,
    float* __restrict__ out)
{
    __shared__ float red[4][64][36];   // 36 KB: [wr*2+wc][lane][9 frags x 4]
    const int tid = threadIdx.x;
    const int wid = tid >> 6, l = tid & 63;
    const int lr = l & 15, lg = l >> 4;
    const int wc = wid & 1, wr = (wid >> 1) & 1, kh = wid >> 2;
    const int r0 = blockIdx.x * 32;
    const int row = r0 + 16 * wr + lr;
    const int colbase = 64 * wc;
    const int kstart = kh * 4096;

    const float* ap = A + (size_t)row * NN + kstart + 8 * lg;
    const float* ep = E + kstart + 8 * lg;
    const __bf16* xp = XB + (size_t)(kstart >> 5) * 4096 + (colbase + lr) * 32 + 8 * lg;
    const __bf16* yp = YB + (size_t)(kstart >> 5) * 4096 + (colbase + lr) * 32 + 8 * lg;
    const float u = E[row];

    const f32x4 zero4 = {0.f, 0.f, 0.f, 0.f};
    f32x4 aD[4], aC[4], aDen = zero4;
    #pragma unroll
    for (int i = 0; i < 4; ++i) { aD[i] = zero4; aC[i] = zero4; }
    bf16x8 ones;
    #pragma unroll
    for (int i = 0; i < 8; ++i) ones[i] = (__bf16)1.0f;

    f32x4 a0A, a1A, e0A, e1A, a0B, a1B, e0B, e1B;
    bf16x8 bxA[4], byA[4], bxB[4], byB[4];
    intptr_t adv = 32;

#define LOADT(S) do {                                                        \
        a0##S = *(const f32x4*)(ap); a1##S = *(const f32x4*)(ap + 4);        \
        e0##S = *(const f32x4*)(ep); e1##S = *(const f32x4*)(ep + 4);        \
        _Pragma("unroll")                                                    \
        for (int c = 0; c < 4; ++c) {                                        \
            bx##S[c] = *(const bf16x8*)(xp + c * 512);                       \
            by##S[c] = *(const bf16x8*)(yp + c * 512);                       \
        }                                                                    \
        ap += adv; ep += adv; xp += adv * 128; yp += adv * 128;              \
    } while (0)

#define COMPT(S) do {                                                        \
        bf16x8 gf;                                                           \
        _Pragma("unroll")                                                    \
        for (int j = 0; j < 4; ++j) {                                        \
            gf[j]     = (__bf16)__expf(u * __builtin_amdgcn_rcpf(u + e0##S[j])); \
            gf[4 + j] = (__bf16)__expf(u * __builtin_amdgcn_rcpf(u + e1##S[j])); \
        }                                                                    \
        const bf16x8 af = pack8(a0##S, a1##S);                               \
        _Pragma("unroll")                                                    \
        for (int c = 0; c < 4; ++c) {                                        \
            aD[c] = mfma16(af, bx##S[c], aD[c]);                             \
            aC[c] = mfma16(gf, by##S[c], aC[c]);                             \
        }                                                                    \
        aDen = mfma16(gf, ones, aDen);                                       \
    } while (0)

    LOADT(A);                          // tile 0
    for (int it = 0; it < 64; ++it) {
        if (it == 63) adv = 0;
        LOADT(B);                      // tile 2it+1 (it=63: tile 127, no advance)
        COMPT(A);                      // tile 2it
        LOADT(A);                      // tile 2it+2 (it=63: dummy re-load of 127)
        COMPT(B);                      // tile 2it+1
    }
#undef LOADT
#undef COMPT

    // ---- cross-kh reduction via LDS (single barrier) ----
    const int grp = wr * 2 + wc;
    if (kh == 1) {
        float* slot = &red[grp][l][0];
        #pragma unroll
        for (int c = 0; c < 4; ++c) {
            *(f32x4*)(slot + 4 * c)      = aD[c];
            *(f32x4*)(slot + 16 + 4 * c) = aC[c];
        }
        *(f32x4*)(slot + 32) = aDen;
    }
    __syncthreads();
    if (kh == 0) {
        const float* slot = &red[grp][l][0];
        #pragma unroll
        for (int c = 0; c < 4; ++c) {
            aD[c] += *(const f32x4*)(slot + 4 * c);
            aC[c] += *(const f32x4*)(slot + 16 + 4 * c);
        }
        aDen += *(const f32x4*)(slot + 32);

        const float omega = fast_sigmoid(omega_logit[0]);
        const float om1 = 1.0f - omega;
        const int rbase = r0 + 16 * wr + 4 * lg;
        #pragma unroll
        for (int c = 0; c < 4; ++c) {
            const int col = colbase + 16 * c + lr;
            const bf16x4 rea4 = *(const bf16x4*)(REAT + (size_t)col * NN + rbase);
            #pragma unroll
            for (int r = 0; r < 4; ++r) {
                const float dv = fmaxf(aD[c][r], 0.0f);
                const float cv = aC[c][r] * __builtin_amdgcn_rcpf(aDen[r]);
                out[(size_t)(rbase + r) * DD + col] = (float)rea4[r] + omega * dv + om1 * cv;
            }
        }
    }
}

extern "C" void kernel_launch(void* const* d_in, const int* in_sizes, int n_in,
                              void* d_out, int out_size, void* d_ws, size_t ws_size,
                              hipStream_t stream) {
    (void)in_sizes; (void)n_in; (void)out_size; (void)ws_size;
    const float* Z   = (const float*)d_in[0];
    const float* A   = (const float*)d_in[1];
    const float* W_D = (const float*)d_in[2];
    const float* W_C = (const float*)d_in[3];
    const float* wV  = (const float*)d_in[4];
    const float* W1  = (const float*)d_in[5];
    const float* b1  = (const float*)d_in[6];
    const float* W2  = (const float*)d_in[7];
    const float* b2  = (const float*)d_in[8];
    const float* omega_logit = (const float*)d_in[9];
    const float* delta_logit = (const float*)d_in[10];
    float* out = (float*)d_out;

    // ws layout: E 32KB | Wb bf16 128KB | XB 2MB | YB 2MB | REAT 2MB (~6.5MB)
    float*  E    = (float*)d_ws;
    __bf16* Wb   = (__bf16*)((char*)d_ws + 32768);
    __bf16* XB   = (__bf16*)((char*)d_ws + 262144);
    __bf16* YB   = (__bf16*)((char*)d_ws + 262144 + 2097152);
    __bf16* REAT = (__bf16*)((char*)d_ws + 262144 + 2 * 2097152);

    k_prep_sE<<<dim3(2048), dim3(256), 0, stream>>>(Z, wV, E);
    k_conv_w<<<dim3(64), dim3(256), 0, stream>>>(W_D, W_C, W1, W2, Wb);
    k_prep2<<<dim3(256), dim3(256), 0, stream>>>(Z, Wb, b1, b2, delta_logit, XB, YB, REAT);
    k_big<<<dim3(256), dim3(512), 0, stream>>>(A, E, XB, YB, REAT, omega_logit, out);
}